// Round 3
// baseline (309.122 us; speedup 1.0000x reference)
//
#include <hip/hip_runtime.h>
#include <hip/hip_bf16.h>
#include <math.h>

#define B_ 32
#define L_ 720
#define N_ 512
#define H_ 16
#define D_ 64
#define TOPK_ 8
#define M_ (B_ * L_)          // 23040 rows
#define RPB 8                 // rows per ring block
#define CRCH 16               // center_raw chunks per batch
#define CRL (L_ / CRCH)       // 45
#define PROWS 32              // rows per fused-tail panel

typedef __bf16 bf16x8 __attribute__((ext_vector_type(8)));
typedef float f32x16 __attribute__((ext_vector_type(16)));

__device__ __forceinline__ f32x16 fzero16() {
    f32x16 z;
    #pragma unroll
    for (int e = 0; e < 16; ++e) z[e] = 0.f;
    return z;
}

__device__ __forceinline__ float sigm(float v) { return 1.f / (1.f + expf(-v)); }

// ---------------------------------------------------------------------------
// Kernel 0: Q = ve@Wq+bq, K = ve@Wk+bk  (512x16 each). grid 16 x 512 thr.
// ---------------------------------------------------------------------------
__global__ __launch_bounds__(512) void qk_kernel(
    const float* __restrict__ ve,
    const float* __restrict__ Wq, const float* __restrict__ bq,
    const float* __restrict__ Wk, const float* __restrict__ bk,
    float* __restrict__ Qm, float* __restrict__ Km)
{
    const int g = blockIdx.x * 512 + threadIdx.x;   // 0..8191
    const int j = g >> 4, h = g & 15;
    const float* vr = ve + j * H_;
    float q = bq[h], k = bk[h];
    #pragma unroll
    for (int m = 0; m < H_; ++m) {
        const float v = vr[m];
        q += v * Wq[m * H_ + h];
        k += v * Wk[m * H_ + h];
    }
    Qm[g] = q;
    Km[g] = k;
}

// ---------------------------------------------------------------------------
// Kernel 1: top-8 neighbors. One wave per row n; shuffle-only selection.
// ---------------------------------------------------------------------------
__global__ __launch_bounds__(64) void topk_kernel(
    const float* __restrict__ Qm, const float* __restrict__ Km,
    float* __restrict__ w_out, int* __restrict__ idx_out)
{
    const int n = blockIdx.x;
    const int lane = threadIdx.x;

    float4 q0, q1, q2, q3;
    {
        const float4* qr = (const float4*)(Qm + n * H_);
        q0 = qr[0]; q1 = qr[1]; q2 = qr[2]; q3 = qr[3];
    }

    float sv[8]; int si[8];
    #pragma unroll
    for (int c = 0; c < 8; ++c) {
        const int j = c * 64 + lane;
        const float4* kr = (const float4*)(Km + j * H_);
        float4 k0 = kr[0], k1 = kr[1], k2 = kr[2], k3 = kr[3];
        float s = q0.x * k0.x + q0.y * k0.y + q0.z * k0.z + q0.w * k0.w
                + q1.x * k1.x + q1.y * k1.y + q1.z * k1.z + q1.w * k1.w
                + q2.x * k2.x + q2.y * k2.y + q2.z * k2.z + q2.w * k2.w
                + q3.x * k3.x + q3.y * k3.y + q3.z * k3.z + q3.w * k3.w;
        sv[c] = (j == n) ? -1e9f : s;
        si[c] = j;
    }

    float keepv[TOPK_]; int keepi[TOPK_];
    #pragma unroll
    for (int k = 0; k < TOPK_; ++k) {
        float bv = sv[0]; int bi = si[0]; int bslot = 0;
        #pragma unroll
        for (int c = 1; c < 8; ++c)
            if (sv[c] > bv || (sv[c] == bv && si[c] < bi)) { bv = sv[c]; bi = si[c]; bslot = c; }
        float v = bv; int i = bi;
        #pragma unroll
        for (int off = 32; off > 0; off >>= 1) {
            float v2 = __shfl_xor(v, off);
            int   i2 = __shfl_xor(i, off);
            if (v2 > v || (v2 == v && i2 < i)) { v = v2; i = i2; }
        }
        keepv[k] = v; keepi[k] = i;
        if (i == bi) sv[bslot] = -INFINITY;
    }

    if (lane == 0) {
        float vmax = keepv[0];
        float ev[TOPK_], esum = 0.f;
        #pragma unroll
        for (int k = 0; k < TOPK_; k++) { ev[k] = expf(keepv[k] - vmax); esum += ev[k]; }
        float inv = 1.f / esum;
        #pragma unroll
        for (int k = 0; k < TOPK_; k++) {
            w_out[n * TOPK_ + k] = ev[k] * inv;
            idx_out[n * TOPK_ + k] = keepi[k];
        }
    }
}

// ---------------------------------------------------------------------------
// Kernel 2: ring gather -> bf16 A matrix, fused with score s = x·Wscore+b.
// ---------------------------------------------------------------------------
__global__ __launch_bounds__(512) void ring_kernel(
    const float* __restrict__ x, const float* __restrict__ w,
    const int* __restrict__ idx,
    const float* __restrict__ Wscore, const float* __restrict__ bscore,
    __hip_bfloat16* __restrict__ ring, float* __restrict__ s)
{
    __shared__ float xs[RPB][N_];
    __shared__ float wsh[N_ * TOPK_];
    __shared__ int   ish[N_ * TOPK_];
    const int t = threadIdx.x;
    const int row0 = blockIdx.x * RPB;

    for (int i = t; i < N_ * TOPK_; i += 512) { wsh[i] = w[i]; ish[i] = idx[i]; }
    {
        const float4* xg = (const float4*)(x + (size_t)row0 * N_);
        float4* xsf = (float4*)&xs[0][0];
        xsf[t] = xg[t];
        xsf[t + 512] = xg[t + 512];
    }
    __syncthreads();

    {
        const int wv = t >> 6, lane = t & 63;
        float sa = 0.f;
        #pragma unroll
        for (int i = 0; i < 8; ++i) sa += xs[wv][lane + i * 64] * Wscore[lane + i * 64];
        for (int off = 32; off > 0; off >>= 1) sa += __shfl_down(sa, off);
        if (lane == 0) s[row0 + wv] = sa + bscore[0];
    }

    float wr[TOPK_]; int ir[TOPK_];
    #pragma unroll
    for (int k = 0; k < TOPK_; ++k) { wr[k] = wsh[t * TOPK_ + k]; ir[k] = ish[t * TOPK_ + k]; }
    #pragma unroll
    for (int r = 0; r < RPB; ++r) {
        float acc = 0.f;
        #pragma unroll
        for (int k = 0; k < TOPK_; ++k) acc += wr[k] * xs[r][ir[k]];
        ring[(size_t)(row0 + r) * N_ + t] = __float2bfloat16(acc);
    }
}

// ---------------------------------------------------------------------------
// Kernel 3: softmax over L per batch (in place on s)
// ---------------------------------------------------------------------------
__global__ __launch_bounds__(256) void attn_softmax_kernel(float* __restrict__ s)
{
    const int b = blockIdx.x;
    const int t = threadIdx.x;
    float* row = s + (size_t)b * L_;

    __shared__ float sm[4];
    __shared__ float sm2[4];

    float lmax = -1e30f;
    for (int l = t; l < L_; l += 256) lmax = fmaxf(lmax, row[l]);
    for (int off = 32; off > 0; off >>= 1) lmax = fmaxf(lmax, __shfl_down(lmax, off));
    if ((t & 63) == 0) sm[t >> 6] = lmax;
    __syncthreads();
    float gmax = fmaxf(fmaxf(sm[0], sm[1]), fmaxf(sm[2], sm[3]));

    float lsum = 0.f;
    for (int l = t; l < L_; l += 256) {
        float e = expf(row[l] - gmax);
        row[l] = e;
        lsum += e;
    }
    for (int off = 32; off > 0; off >>= 1) lsum += __shfl_down(lsum, off);
    if ((t & 63) == 0) sm2[t >> 6] = lsum;
    __syncthreads();
    float inv = 1.f / (sm2[0] + sm2[1] + sm2[2] + sm2[3]);
    for (int l = t; l < L_; l += 256) row[l] *= inv;
}

// ---------------------------------------------------------------------------
// Kernel 4: partial center_raw. grid B_*CRCH: b = bx>>4, chunk c = bx&15.
// ---------------------------------------------------------------------------
__global__ __launch_bounds__(512) void center_raw_kernel(
    const float* __restrict__ x, const float* __restrict__ attn,
    float* __restrict__ craw_p)
{
    const int b = blockIdx.x >> 4;
    const int c = blockIdx.x & 15;
    const int n = threadIdx.x;
    __shared__ float ash[CRL];
    const int l0 = c * CRL;
    if (n < CRL) ash[n] = attn[b * L_ + l0 + n];
    __syncthreads();
    const float* xb = x + ((size_t)b * L_ + l0) * N_;
    float acc = 0.f;
    #pragma unroll 3
    for (int l = 0; l < CRL; l++) acc += ash[l] * xb[(size_t)l * N_ + n];
    craw_p[(size_t)(b * CRCH + c) * N_ + n] = acc;
}

__device__ __forceinline__ float gelu_exact(float v) {
    return 0.5f * v * (1.0f + erff(v * 0.70710678118654752440f));
}

// ---------------------------------------------------------------------------
// Kernel 5: reduce partials + center MLP -> center. grid B_, 512 thr.
// ---------------------------------------------------------------------------
__global__ __launch_bounds__(512) void center_mlp_kernel(
    const float* __restrict__ craw_p,
    const float* __restrict__ Wc1, const float* __restrict__ bc1,
    const float* __restrict__ Wc2, const float* __restrict__ bc2,
    const float* __restrict__ Wcn, const float* __restrict__ bcn,
    float* __restrict__ center)
{
    const int b = blockIdx.x;
    const int t = threadIdx.x;
    const int col = t & 63;
    const int seg = t >> 6;
    __shared__ float cr[N_];
    __shared__ float psum[8][D_];
    __shared__ float h1[D_];
    __shared__ float h2[D_];

    {
        float acc = 0.f;
        #pragma unroll
        for (int c = 0; c < CRCH; ++c) acc += craw_p[(size_t)(b * CRCH + c) * N_ + t];
        cr[t] = acc;
    }
    __syncthreads();
    {
        float p = 0.f;
        #pragma unroll 8
        for (int m = seg * 64; m < seg * 64 + 64; ++m) p += cr[m] * Wc1[m * D_ + col];
        psum[seg][col] = p;
    }
    __syncthreads();
    if (t < D_) {
        float acc = bc1[t];
        #pragma unroll
        for (int s2 = 0; s2 < 8; ++s2) acc += psum[s2][t];
        h1[t] = gelu_exact(acc);
    }
    __syncthreads();
    if (t < D_) {
        float acc = bc2[t];
        #pragma unroll 8
        for (int j = 0; j < D_; j++) acc += h1[j] * Wc2[j * D_ + t];
        h2[t] = gelu_exact(acc);
    }
    __syncthreads();
    {
        float acc = bcn[t];
        #pragma unroll 8
        for (int j = 0; j < D_; j++) acc += h2[j] * Wcn[j * N_ + t];
        center[b * N_ + t] = acc;
    }
}

// ---------------------------------------------------------------------------
// Kernel 6: cg[b,n] = center[b]·Wg[512+.,n] + bg[n].
// ---------------------------------------------------------------------------
__global__ __launch_bounds__(512) void cg_kernel(
    const float* __restrict__ center, const float* __restrict__ Wg,
    const float* __restrict__ bg, float* __restrict__ cg)
{
    const int nc = blockIdx.x;
    const int b  = blockIdx.y;
    const int t  = threadIdx.x;
    const int col = nc * 64 + (t & 63);
    const int seg = t >> 6;
    __shared__ float cs[N_];
    __shared__ float psum[8][64];

    cs[t] = center[b * N_ + t];
    __syncthreads();
    {
        float p = 0.f;
        const float* wp = Wg + (size_t)(N_ + seg * 64) * N_ + col;
        #pragma unroll 8
        for (int m = 0; m < 64; ++m) { p += cs[seg * 64 + m] * wp[0]; wp += N_; }
        psum[seg][t & 63] = p;
    }
    __syncthreads();
    if (t < 64) {
        float acc = bg[nc * 64 + t];
        #pragma unroll
        for (int s2 = 0; s2 < 8; ++s2) acc += psum[s2][t];
        cg[b * N_ + nc * 64 + t] = acc;
    }
}

// ---------------------------------------------------------------------------
// Kernel 7: transpose+convert Wg-top / Wf to bf16 (N x K row-major)
// ---------------------------------------------------------------------------
__global__ __launch_bounds__(256) void convert_kernel(
    const float* __restrict__ Wg, const float* __restrict__ Wf,
    __hip_bfloat16* __restrict__ WgT, __hip_bfloat16* __restrict__ WfT)
{
    const int n = blockIdx.x & 511;
    const bool isf = blockIdx.x >= 512;
    const float* src = isf ? Wf : Wg;
    __hip_bfloat16* dst = isf ? WfT : WgT;
    for (int k = threadIdx.x; k < N_; k += 256)
        dst[n * N_ + k] = __float2bfloat16(src[(size_t)k * N_ + n]);
}

// ---------------------------------------------------------------------------
// Kernel 8: fused tail. One block = 32-row panel x all 512 cols.
//   gate GEMM (ring@WgT^T + cg -> sigmoid mix)  -> fused (LDS, bf16)
//   out GEMM  (fused@WfT^T + bf + x)            -> LN -> out
// Swapped-operand MFMA: mfma(W_frag, data_frag) puts the sample row in the
// lane dim (each lane owns ONE row, cols in runs of 4) -> float4 x/out I/O,
// b64 LDS fused writes, LN row-reduce = per-lane sum + shfl_xor(32).
// B-fragments (WgT/WfT rows) have no intra-block reuse -> loaded directly
// from global (L2-resident, 1 MB/block). LDS ~48 KB -> 3 blocks/CU.
// ---------------------------------------------------------------------------
__global__ __launch_bounds__(256) void fused_tail_kernel(
    const __hip_bfloat16* __restrict__ ring,
    const __hip_bfloat16* __restrict__ WgT,
    const __hip_bfloat16* __restrict__ WfT,
    const float* __restrict__ cg,
    const float* __restrict__ center,
    const float* __restrict__ x,
    const float* __restrict__ bfv,
    const float* __restrict__ gamma,
    const float* __restrict__ beta,
    float* __restrict__ out)
{
    __shared__ __attribute__((aligned(16))) __hip_bfloat16 fsh[PROWS * N_]; // 32 KB, swizzled
    __shared__ __attribute__((aligned(16))) float cgs[2][N_];
    __shared__ __attribute__((aligned(16))) float cents[2][N_];
    __shared__ __attribute__((aligned(16))) float bfs[N_];
    __shared__ __attribute__((aligned(16))) float gms[N_];
    __shared__ __attribute__((aligned(16))) float bts[N_];
    __shared__ float ps[4][PROWS];
    __shared__ float pq[4][PROWS];

    const int tid  = threadIdx.x;
    const int wv   = tid >> 6;
    const int lane = tid & 63;
    const int m    = lane & 31;
    const int half = lane >> 5;
    const int row0 = blockIdx.x * PROWS;
    const int b0   = row0 / L_;
    const int b1   = (row0 + PROWS - 1) / L_;
    const int rowg = row0 + m;                      // this lane's sample row
    const int bsel = (rowg / L_ != b0) ? 1 : 0;

    // stage per-block tables (cg/center rows of the 1-2 batches touched + vecs)
    for (int i = tid; i < N_; i += 256) {
        cgs[0][i]   = cg[b0 * N_ + i];
        cgs[1][i]   = cg[b1 * N_ + i];
        cents[0][i] = center[b0 * N_ + i];
        cents[1][i] = center[b1 * N_ + i];
        bfs[i] = bfv[i];
        gms[i] = gamma[i];
        bts[i] = beta[i];
    }

    // ---- gate GEMM: acc_g = ring_panel @ WgT^T for col-tiles (g*4+wv)*32 ----
    f32x16 ac0 = fzero16(), ac1 = fzero16(), ac2 = fzero16(), ac3 = fzero16();
    {
        const __hip_bfloat16* rb = ring + (size_t)rowg * N_ + half * 8;
        const __hip_bfloat16* w0 = WgT + (size_t)(( 0 + wv) * 32 + m) * N_ + half * 8;
        const __hip_bfloat16* w1 = WgT + (size_t)(( 4 + wv) * 32 + m) * N_ + half * 8;
        const __hip_bfloat16* w2 = WgT + (size_t)(( 8 + wv) * 32 + m) * N_ + half * 8;
        const __hip_bfloat16* w3 = WgT + (size_t)((12 + wv) * 32 + m) * N_ + half * 8;
        #pragma unroll 4
        for (int kc = 0; kc < 32; ++kc) {
            const int off = kc * 16;
            const bf16x8 b = *(const bf16x8*)(rb + off);
            ac0 = __builtin_amdgcn_mfma_f32_32x32x16_bf16(*(const bf16x8*)(w0 + off), b, ac0, 0, 0, 0);
            ac1 = __builtin_amdgcn_mfma_f32_32x32x16_bf16(*(const bf16x8*)(w1 + off), b, ac1, 0, 0, 0);
            ac2 = __builtin_amdgcn_mfma_f32_32x32x16_bf16(*(const bf16x8*)(w2 + off), b, ac2, 0, 0, 0);
            ac3 = __builtin_amdgcn_mfma_f32_32x32x16_bf16(*(const bf16x8*)(w3 + off), b, ac3, 0, 0, 0);
        }
    }
    __syncthreads();   // tables staged; acc ready

    // ---- gate epilogue: sigmoid mix -> fused (bf16, swizzled LDS) ----
#define GEPI(AC, G)                                                            \
    {                                                                          \
        const int ntb = ((G) * 4 + wv) * 32;                                   \
        _Pragma("unroll") for (int q = 0; q < 4; ++q) {                        \
            const int nb = ntb + 8 * q + 4 * half;                             \
            const float4 cgq = *(const float4*)&cgs[bsel][nb];                 \
            const float4 ctq = *(const float4*)&cents[bsel][nb];               \
            const uint2 rvp = *(const uint2*)(ring + (size_t)rowg * N_ + nb);  \
            const float rv0 = __uint_as_float((rvp.x & 0xffffu) << 16);        \
            const float rv1 = __uint_as_float((rvp.x >> 16) << 16);            \
            const float rv2 = __uint_as_float((rvp.y & 0xffffu) << 16);        \
            const float rv3 = __uint_as_float((rvp.y >> 16) << 16);            \
            const float g0 = sigm(AC[4 * q + 0] + cgq.x);                      \
            const float g1 = sigm(AC[4 * q + 1] + cgq.y);                      \
            const float g2 = sigm(AC[4 * q + 2] + cgq.z);                      \
            const float g3 = sigm(AC[4 * q + 3] + cgq.w);                      \
            const float f0 = g0 * rv0 + (1.f - g0) * ctq.x;                    \
            const float f1 = g1 * rv1 + (1.f - g1) * ctq.y;                    \
            const float f2 = g2 * rv2 + (1.f - g2) * ctq.z;                    \
            const float f3 = g3 * rv3 + (1.f - g3) * ctq.w;                    \
            uint2 wpk;                                                         \
            wpk.x = (unsigned)__builtin_bit_cast(unsigned short, __float2bfloat16(f0)) |        \
                    ((unsigned)__builtin_bit_cast(unsigned short, __float2bfloat16(f1)) << 16); \
            wpk.y = (unsigned)__builtin_bit_cast(unsigned short, __float2bfloat16(f2)) |        \
                    ((unsigned)__builtin_bit_cast(unsigned short, __float2bfloat16(f3)) << 16); \
            *(uint2*)((char*)fsh + m * 1024 + (((nb >> 3) ^ (m & 7)) << 4) + ((nb & 7) << 1)) = wpk; \
        }                                                                      \
    }
    GEPI(ac0, 0) GEPI(ac1, 1) GEPI(ac2, 2) GEPI(ac3, 3)
    __syncthreads();   // fused complete

    // ---- out GEMM: oc_g = fused_panel @ WfT^T ----
    f32x16 oc0 = fzero16(), oc1 = fzero16(), oc2 = fzero16(), oc3 = fzero16();
    {
        const char* fb = (const char*)fsh + m * 1024;
        const __hip_bfloat16* v0 = WfT + (size_t)(( 0 + wv) * 32 + m) * N_ + half * 8;
        const __hip_bfloat16* v1 = WfT + (size_t)(( 4 + wv) * 32 + m) * N_ + half * 8;
        const __hip_bfloat16* v2 = WfT + (size_t)(( 8 + wv) * 32 + m) * N_ + half * 8;
        const __hip_bfloat16* v3 = WfT + (size_t)((12 + wv) * 32 + m) * N_ + half * 8;
        #pragma unroll 4
        for (int kc = 0; kc < 32; ++kc) {
            const int c8 = kc * 2 + half;
            const bf16x8 b = *(const bf16x8*)(fb + ((c8 ^ (m & 7)) << 4));
            const int off = kc * 16;
            oc0 = __builtin_amdgcn_mfma_f32_32x32x16_bf16(*(const bf16x8*)(v0 + off), b, oc0, 0, 0, 0);
            oc1 = __builtin_amdgcn_mfma_f32_32x32x16_bf16(*(const bf16x8*)(v1 + off), b, oc1, 0, 0, 0);
            oc2 = __builtin_amdgcn_mfma_f32_32x32x16_bf16(*(const bf16x8*)(v2 + off), b, oc2, 0, 0, 0);
            oc3 = __builtin_amdgcn_mfma_f32_32x32x16_bf16(*(const bf16x8*)(v3 + off), b, oc3, 0, 0, 0);
        }
    }

    // ---- out epilogue: + bf + x residual; accumulate LN stats in-place ----
    float lsum = 0.f, lsq = 0.f;
#define OEPI(AC, G)                                                            \
    {                                                                          \
        const int ntb = ((G) * 4 + wv) * 32;                                   \
        _Pragma("unroll") for (int q = 0; q < 4; ++q) {                        \
            const int nb = ntb + 8 * q + 4 * half;                             \
            const float4 bq = *(const float4*)&bfs[nb];                        \
            const float4 xq = *(const float4*)(x + (size_t)rowg * N_ + nb);    \
            AC[4 * q + 0] += bq.x + xq.x;                                      \
            AC[4 * q + 1] += bq.y + xq.y;                                      \
            AC[4 * q + 2] += bq.z + xq.z;                                      \
            AC[4 * q + 3] += bq.w + xq.w;                                      \
            lsum += AC[4 * q + 0] + AC[4 * q + 1] + AC[4 * q + 2] + AC[4 * q + 3]; \
            lsq  += AC[4 * q + 0] * AC[4 * q + 0] + AC[4 * q + 1] * AC[4 * q + 1]  \
                  + AC[4 * q + 2] * AC[4 * q + 2] + AC[4 * q + 3] * AC[4 * q + 3]; \
        }                                                                      \
    }
    OEPI(oc0, 0) OEPI(oc1, 1) OEPI(oc2, 2) OEPI(oc3, 3)

    // ---- LN: lane holds 64 of its row's 512 cols; partner lane (xor 32)
    //      holds another 64; 4 waves hold the rest ----
    lsum += __shfl_xor(lsum, 32);
    lsq  += __shfl_xor(lsq, 32);
    if (half == 0) { ps[wv][m] = lsum; pq[wv][m] = lsq; }
    __syncthreads();
    const float S   = ps[0][m] + ps[1][m] + ps[2][m] + ps[3][m];
    const float Q2  = pq[0][m] + pq[1][m] + pq[2][m] + pq[3][m];
    const float mu  = S * (1.0f / N_);
    const float var = Q2 * (1.0f / N_) - mu * mu;
    const float inv = rsqrtf(var + 1e-5f);

#define LSTORE(AC, G)                                                          \
    {                                                                          \
        const int ntb = ((G) * 4 + wv) * 32;                                   \
        _Pragma("unroll") for (int q = 0; q < 4; ++q) {                        \
            const int nb = ntb + 8 * q + 4 * half;                             \
            const float4 g4 = *(const float4*)&gms[nb];                        \
            const float4 b4 = *(const float4*)&bts[nb];                        \
            float4 o;                                                          \
            o.x = (AC[4 * q + 0] - mu) * inv * g4.x + b4.x;                    \
            o.y = (AC[4 * q + 1] - mu) * inv * g4.y + b4.y;                    \
            o.z = (AC[4 * q + 2] - mu) * inv * g4.z + b4.z;                    \
            o.w = (AC[4 * q + 3] - mu) * inv * g4.w + b4.w;                    \
            *(float4*)(out + (size_t)rowg * N_ + nb) = o;                      \
        }                                                                      \
    }
    LSTORE(oc0, 0) LSTORE(oc1, 1) LSTORE(oc2, 2) LSTORE(oc3, 3)
}

// ---------------------------------------------------------------------------
extern "C" void kernel_launch(void* const* d_in, const int* in_sizes, int n_in,
                              void* d_out, int out_size, void* d_ws, size_t ws_size,
                              hipStream_t stream) {
    const float* x       = (const float*)d_in[0];
    const float* ve      = (const float*)d_in[1];
    const float* Wq      = (const float*)d_in[2];
    const float* bq      = (const float*)d_in[3];
    const float* Wk      = (const float*)d_in[4];
    const float* bk      = (const float*)d_in[5];
    const float* Wscore  = (const float*)d_in[6];
    const float* bscore  = (const float*)d_in[7];
    const float* Wc1     = (const float*)d_in[8];
    const float* bc1     = (const float*)d_in[9];
    const float* Wc2     = (const float*)d_in[10];
    const float* bc2     = (const float*)d_in[11];
    const float* Wcn     = (const float*)d_in[12];
    const float* bcn     = (const float*)d_in[13];
    const float* Wg      = (const float*)d_in[14];
    const float* bg      = (const float*)d_in[15];
    const float* Wf      = (const float*)d_in[16];
    const float* bf      = (const float*)d_in[17];
    const float* gamma   = (const float*)d_in[18];
    const float* beta    = (const float*)d_in[19];
    float* out = (float*)d_out;

    char* p = (char*)d_ws;
    float* ws_w    = (float*)p; p += N_ * TOPK_ * sizeof(float);
    int*   ws_idx  = (int*)p;   p += N_ * TOPK_ * sizeof(int);
    float* ws_s    = (float*)p; p += B_ * L_ * sizeof(float);
    float* ws_crp  = (float*)p; p += B_ * CRCH * N_ * sizeof(float);
    float* ws_cent = (float*)p; p += B_ * N_ * sizeof(float);
    float* ws_cg   = (float*)p; p += B_ * N_ * sizeof(float);
    float* ws_Q    = (float*)p; p += N_ * H_ * sizeof(float);
    float* ws_K    = (float*)p; p += N_ * H_ * sizeof(float);
    __hip_bfloat16* ws_ring  = (__hip_bfloat16*)p; p += (size_t)M_ * N_ * sizeof(__hip_bfloat16);
    __hip_bfloat16* ws_WgT   = (__hip_bfloat16*)p; p += (size_t)N_ * N_ * sizeof(__hip_bfloat16);
    __hip_bfloat16* ws_WfT   = (__hip_bfloat16*)p; p += (size_t)N_ * N_ * sizeof(__hip_bfloat16);

    convert_kernel<<<1024, 256, 0, stream>>>(Wg, Wf, ws_WgT, ws_WfT);
    qk_kernel<<<16, 512, 0, stream>>>(ve, Wq, bq, Wk, bk, ws_Q, ws_K);
    topk_kernel<<<N_, 64, 0, stream>>>(ws_Q, ws_K, ws_w, ws_idx);
    ring_kernel<<<M_ / RPB, 512, 0, stream>>>(x, ws_w, ws_idx, Wscore, bscore,
                                              ws_ring, ws_s);
    attn_softmax_kernel<<<B_, 256, 0, stream>>>(ws_s);
    center_raw_kernel<<<B_ * CRCH, 512, 0, stream>>>(x, ws_s, ws_crp);
    center_mlp_kernel<<<B_, 512, 0, stream>>>(ws_crp, Wc1, bc1, Wc2, bc2,
                                              Wcn, bcn, ws_cent);
    cg_kernel<<<dim3(8, B_), 512, 0, stream>>>(ws_cent, Wg, bg, ws_cg);
    fused_tail_kernel<<<M_ / PROWS, 256, 0, stream>>>(ws_ring, ws_WgT, ws_WfT,
                                                      ws_cg, ws_cent, x, bf,
                                                      gamma, beta, out);
}

// Round 4
// 267.132 us; speedup vs baseline: 1.1572x; 1.1572x over previous
//
#include <hip/hip_runtime.h>
#include <hip/hip_bf16.h>
#include <math.h>

#define B_ 32
#define L_ 720
#define N_ 512
#define H_ 16
#define D_ 64
#define TOPK_ 8
#define M_ (B_ * L_)          // 23040 rows
#define RPB 8                 // rows per ring block
#define CRCH 16               // center_raw chunks per batch
#define CRL (L_ / CRCH)       // 45
#define OROWS 64              // rows per out+ln panel

typedef __bf16 bf16x8 __attribute__((ext_vector_type(8)));
typedef float f32x16 __attribute__((ext_vector_type(16)));

// ---------------------------------------------------------------------------
// async 16B global -> LDS (dest = wave-uniform lds base + lane*16)
// ---------------------------------------------------------------------------
__device__ __forceinline__ void async_cp16(const __hip_bfloat16* g, __hip_bfloat16* l) {
    __builtin_amdgcn_global_load_lds(
        (const __attribute__((address_space(1))) void*)g,
        (__attribute__((address_space(3))) void*)l, 16, 0, 0);
}

__device__ __forceinline__ bf16x8 frag_ld(const __hip_bfloat16* base, int row, int j0) {
    return *(const bf16x8*)(base + row * 64 + (((j0) ^ (row & 7)) << 3));
}

__device__ __forceinline__ f32x16 fzero16() {
    f32x16 z;
    #pragma unroll
    for (int e = 0; e < 16; ++e) z[e] = 0.f;
    return z;
}

// ---------------------------------------------------------------------------
// Kernel 0: Q = ve@Wq+bq, K = ve@Wk+bk  (512x16 each). grid 16 x 512 thr.
// ---------------------------------------------------------------------------
__global__ __launch_bounds__(512) void qk_kernel(
    const float* __restrict__ ve,
    const float* __restrict__ Wq, const float* __restrict__ bq,
    const float* __restrict__ Wk, const float* __restrict__ bk,
    float* __restrict__ Qm, float* __restrict__ Km)
{
    const int g = blockIdx.x * 512 + threadIdx.x;   // 0..8191
    const int j = g >> 4, h = g & 15;
    const float* vr = ve + j * H_;
    float q = bq[h], k = bk[h];
    #pragma unroll
    for (int m = 0; m < H_; ++m) {
        const float v = vr[m];
        q += v * Wq[m * H_ + h];
        k += v * Wk[m * H_ + h];
    }
    Qm[g] = q;
    Km[g] = k;
}

// ---------------------------------------------------------------------------
// Kernel 1: top-8 neighbors. One wave per row n; shuffle-only selection.
// ---------------------------------------------------------------------------
__global__ __launch_bounds__(64) void topk_kernel(
    const float* __restrict__ Qm, const float* __restrict__ Km,
    float* __restrict__ w_out, int* __restrict__ idx_out)
{
    const int n = blockIdx.x;
    const int lane = threadIdx.x;

    float4 q0, q1, q2, q3;
    {
        const float4* qr = (const float4*)(Qm + n * H_);
        q0 = qr[0]; q1 = qr[1]; q2 = qr[2]; q3 = qr[3];
    }

    float sv[8]; int si[8];
    #pragma unroll
    for (int c = 0; c < 8; ++c) {
        const int j = c * 64 + lane;
        const float4* kr = (const float4*)(Km + j * H_);
        float4 k0 = kr[0], k1 = kr[1], k2 = kr[2], k3 = kr[3];
        float s = q0.x * k0.x + q0.y * k0.y + q0.z * k0.z + q0.w * k0.w
                + q1.x * k1.x + q1.y * k1.y + q1.z * k1.z + q1.w * k1.w
                + q2.x * k2.x + q2.y * k2.y + q2.z * k2.z + q2.w * k2.w
                + q3.x * k3.x + q3.y * k3.y + q3.z * k3.z + q3.w * k3.w;
        sv[c] = (j == n) ? -1e9f : s;
        si[c] = j;
    }

    float keepv[TOPK_]; int keepi[TOPK_];
    #pragma unroll
    for (int k = 0; k < TOPK_; ++k) {
        float bv = sv[0]; int bi = si[0]; int bslot = 0;
        #pragma unroll
        for (int c = 1; c < 8; ++c)
            if (sv[c] > bv || (sv[c] == bv && si[c] < bi)) { bv = sv[c]; bi = si[c]; bslot = c; }
        float v = bv; int i = bi;
        #pragma unroll
        for (int off = 32; off > 0; off >>= 1) {
            float v2 = __shfl_xor(v, off);
            int   i2 = __shfl_xor(i, off);
            if (v2 > v || (v2 == v && i2 < i)) { v = v2; i = i2; }
        }
        keepv[k] = v; keepi[k] = i;
        if (i == bi) sv[bslot] = -INFINITY;
    }

    if (lane == 0) {
        float vmax = keepv[0];
        float ev[TOPK_], esum = 0.f;
        #pragma unroll
        for (int k = 0; k < TOPK_; k++) { ev[k] = expf(keepv[k] - vmax); esum += ev[k]; }
        float inv = 1.f / esum;
        #pragma unroll
        for (int k = 0; k < TOPK_; k++) {
            w_out[n * TOPK_ + k] = ev[k] * inv;
            idx_out[n * TOPK_ + k] = keepi[k];
        }
    }
}

// ---------------------------------------------------------------------------
// Kernel 2: ring gather -> bf16 A matrix, fused with score s = x·Wscore+b.
// ---------------------------------------------------------------------------
__global__ __launch_bounds__(512) void ring_kernel(
    const float* __restrict__ x, const float* __restrict__ w,
    const int* __restrict__ idx,
    const float* __restrict__ Wscore, const float* __restrict__ bscore,
    __hip_bfloat16* __restrict__ ring, float* __restrict__ s)
{
    __shared__ float xs[RPB][N_];
    __shared__ float wsh[N_ * TOPK_];
    __shared__ int   ish[N_ * TOPK_];
    const int t = threadIdx.x;
    const int row0 = blockIdx.x * RPB;

    for (int i = t; i < N_ * TOPK_; i += 512) { wsh[i] = w[i]; ish[i] = idx[i]; }
    {
        const float4* xg = (const float4*)(x + (size_t)row0 * N_);
        float4* xsf = (float4*)&xs[0][0];
        xsf[t] = xg[t];
        xsf[t + 512] = xg[t + 512];
    }
    __syncthreads();

    {
        const int wv = t >> 6, lane = t & 63;
        float sa = 0.f;
        #pragma unroll
        for (int i = 0; i < 8; ++i) sa += xs[wv][lane + i * 64] * Wscore[lane + i * 64];
        for (int off = 32; off > 0; off >>= 1) sa += __shfl_down(sa, off);
        if (lane == 0) s[row0 + wv] = sa + bscore[0];
    }

    float wr[TOPK_]; int ir[TOPK_];
    #pragma unroll
    for (int k = 0; k < TOPK_; ++k) { wr[k] = wsh[t * TOPK_ + k]; ir[k] = ish[t * TOPK_ + k]; }
    #pragma unroll
    for (int r = 0; r < RPB; ++r) {
        float acc = 0.f;
        #pragma unroll
        for (int k = 0; k < TOPK_; ++k) acc += wr[k] * xs[r][ir[k]];
        ring[(size_t)(row0 + r) * N_ + t] = __float2bfloat16(acc);
    }
}

// ---------------------------------------------------------------------------
// Kernel 3: softmax over L per batch (in place on s)
// ---------------------------------------------------------------------------
__global__ __launch_bounds__(256) void attn_softmax_kernel(float* __restrict__ s)
{
    const int b = blockIdx.x;
    const int t = threadIdx.x;
    float* row = s + (size_t)b * L_;

    __shared__ float sm[4];
    __shared__ float sm2[4];

    float lmax = -1e30f;
    for (int l = t; l < L_; l += 256) lmax = fmaxf(lmax, row[l]);
    for (int off = 32; off > 0; off >>= 1) lmax = fmaxf(lmax, __shfl_down(lmax, off));
    if ((t & 63) == 0) sm[t >> 6] = lmax;
    __syncthreads();
    float gmax = fmaxf(fmaxf(sm[0], sm[1]), fmaxf(sm[2], sm[3]));

    float lsum = 0.f;
    for (int l = t; l < L_; l += 256) {
        float e = expf(row[l] - gmax);
        row[l] = e;
        lsum += e;
    }
    for (int off = 32; off > 0; off >>= 1) lsum += __shfl_down(lsum, off);
    if ((t & 63) == 0) sm2[t >> 6] = lsum;
    __syncthreads();
    float inv = 1.f / (sm2[0] + sm2[1] + sm2[2] + sm2[3]);
    for (int l = t; l < L_; l += 256) row[l] *= inv;
}

// ---------------------------------------------------------------------------
// Kernel 4: partial center_raw. grid B_*CRCH: b = bx>>4, chunk c = bx&15.
// ---------------------------------------------------------------------------
__global__ __launch_bounds__(512) void center_raw_kernel(
    const float* __restrict__ x, const float* __restrict__ attn,
    float* __restrict__ craw_p)
{
    const int b = blockIdx.x >> 4;
    const int c = blockIdx.x & 15;
    const int n = threadIdx.x;
    __shared__ float ash[CRL];
    const int l0 = c * CRL;
    if (n < CRL) ash[n] = attn[b * L_ + l0 + n];
    __syncthreads();
    const float* xb = x + ((size_t)b * L_ + l0) * N_;
    float acc = 0.f;
    #pragma unroll 3
    for (int l = 0; l < CRL; l++) acc += ash[l] * xb[(size_t)l * N_ + n];
    craw_p[(size_t)(b * CRCH + c) * N_ + n] = acc;
}

__device__ __forceinline__ float gelu_exact(float v) {
    return 0.5f * v * (1.0f + erff(v * 0.70710678118654752440f));
}

// ---------------------------------------------------------------------------
// Kernel 5: reduce partials + center MLP -> center. grid B_, 512 thr.
// ---------------------------------------------------------------------------
__global__ __launch_bounds__(512) void center_mlp_kernel(
    const float* __restrict__ craw_p,
    const float* __restrict__ Wc1, const float* __restrict__ bc1,
    const float* __restrict__ Wc2, const float* __restrict__ bc2,
    const float* __restrict__ Wcn, const float* __restrict__ bcn,
    float* __restrict__ center)
{
    const int b = blockIdx.x;
    const int t = threadIdx.x;
    const int col = t & 63;
    const int seg = t >> 6;
    __shared__ float cr[N_];
    __shared__ float psum[8][D_];
    __shared__ float h1[D_];
    __shared__ float h2[D_];

    {
        float acc = 0.f;
        #pragma unroll
        for (int c = 0; c < CRCH; ++c) acc += craw_p[(size_t)(b * CRCH + c) * N_ + t];
        cr[t] = acc;
    }
    __syncthreads();
    {
        float p = 0.f;
        #pragma unroll 8
        for (int m = seg * 64; m < seg * 64 + 64; ++m) p += cr[m] * Wc1[m * D_ + col];
        psum[seg][col] = p;
    }
    __syncthreads();
    if (t < D_) {
        float acc = bc1[t];
        #pragma unroll
        for (int s2 = 0; s2 < 8; ++s2) acc += psum[s2][t];
        h1[t] = gelu_exact(acc);
    }
    __syncthreads();
    if (t < D_) {
        float acc = bc2[t];
        #pragma unroll 8
        for (int j = 0; j < D_; j++) acc += h1[j] * Wc2[j * D_ + t];
        h2[t] = gelu_exact(acc);
    }
    __syncthreads();
    {
        float acc = bcn[t];
        #pragma unroll 8
        for (int j = 0; j < D_; j++) acc += h2[j] * Wcn[j * N_ + t];
        center[b * N_ + t] = acc;
    }
}

// ---------------------------------------------------------------------------
// Kernel 6: cg[b,n] = center[b]·Wg[512+.,n] + bg[n].
// ---------------------------------------------------------------------------
__global__ __launch_bounds__(512) void cg_kernel(
    const float* __restrict__ center, const float* __restrict__ Wg,
    const float* __restrict__ bg, float* __restrict__ cg)
{
    const int nc = blockIdx.x;
    const int b  = blockIdx.y;
    const int t  = threadIdx.x;
    const int col = nc * 64 + (t & 63);
    const int seg = t >> 6;
    __shared__ float cs[N_];
    __shared__ float psum[8][64];

    cs[t] = center[b * N_ + t];
    __syncthreads();
    {
        float p = 0.f;
        const float* wp = Wg + (size_t)(N_ + seg * 64) * N_ + col;
        #pragma unroll 8
        for (int m = 0; m < 64; ++m) { p += cs[seg * 64 + m] * wp[0]; wp += N_; }
        psum[seg][t & 63] = p;
    }
    __syncthreads();
    if (t < 64) {
        float acc = bg[nc * 64 + t];
        #pragma unroll
        for (int s2 = 0; s2 < 8; ++s2) acc += psum[s2][t];
        cg[b * N_ + nc * 64 + t] = acc;
    }
}

// ---------------------------------------------------------------------------
// Kernel 7: transpose+convert Wg-top / Wf to bf16 (N x K row-major)
// ---------------------------------------------------------------------------
__global__ __launch_bounds__(256) void convert_kernel(
    const float* __restrict__ Wg, const float* __restrict__ Wf,
    __hip_bfloat16* __restrict__ WgT, __hip_bfloat16* __restrict__ WfT)
{
    const int n = blockIdx.x & 511;
    const bool isf = blockIdx.x >= 512;
    const float* src = isf ? Wf : Wg;
    __hip_bfloat16* dst = isf ? WfT : WgT;
    for (int k = threadIdx.x; k < N_; k += 256)
        dst[n * N_ + k] = __float2bfloat16(src[(size_t)k * N_ + n]);
}

// ---------------------------------------------------------------------------
// GEMM core (R2-proven): C(64x64) = A(64x512) @ BT(64x512)^T.
// grid (360,8), 16 KB LDS, 2-phase __syncthreads, ~8 blocks/CU.
// ---------------------------------------------------------------------------
#define GEMM_BODY(EPILOGUE)                                                    \
    __shared__ __hip_bfloat16 Ash[64 * 64];                                    \
    __shared__ __hip_bfloat16 Bsh[64 * 64];                                    \
    const int tid  = threadIdx.x;                                              \
    const int lane = tid & 63;                                                 \
    const int wv   = tid >> 6;                                                 \
    const int m32  = lane & 31;                                                \
    const int half = lane >> 5;                                                \
    const int wr   = wv >> 1;                                                  \
    const int wc   = wv & 1;                                                   \
    const int row0 = blockIdx.x * 64;                                          \
    const int n0   = blockIdx.y * 64;                                          \
    const int swz  = (lane & 7) ^ (lane >> 3);                                 \
    const int rln  = lane >> 3;                                                \
    f32x16 acc;                                                                \
    _Pragma("unroll") for (int e = 0; e < 16; e++) acc[e] = 0.f;               \
    for (int step = 0; step < 8; ++step) {                                     \
        const int k0 = step * 64;                                              \
        const __hip_bfloat16* Ab = A  + (size_t)row0 * N_ + k0 + swz * 8;      \
        const __hip_bfloat16* Bb = BT + (size_t)n0   * N_ + k0 + swz * 8;      \
        __syncthreads();                                                       \
        _Pragma("unroll") for (int j = 0; j < 2; ++j) {                        \
            const int r = j * 32 + wv * 8 + rln;                               \
            const int lb = (j * 256 + wv * 64) * 8;                            \
            async_cp16(Ab + (size_t)r * N_, Ash + lb);                         \
            async_cp16(Bb + (size_t)r * N_, Bsh + lb);                         \
        }                                                                      \
        __syncthreads();                                                       \
        _Pragma("unroll") for (int ks = 0; ks < 4; ++ks) {                     \
            const int j0 = ks * 2 + half;                                      \
            bf16x8 a0 = frag_ld(Ash, wr * 32 + m32, j0);                       \
            bf16x8 b0 = frag_ld(Bsh, wc * 32 + m32, j0);                       \
            acc = __builtin_amdgcn_mfma_f32_32x32x16_bf16(a0, b0, acc, 0, 0, 0); \
        }                                                                      \
    }                                                                          \
    _Pragma("unroll") for (int reg = 0; reg < 16; ++reg) {                     \
        const int rg  = row0 + wr * 32 +                                       \
                        (reg & 3) + 8 * (reg >> 2) + 4 * half;                 \
        const int col = n0 + wc * 32 + m32;                                    \
        const float aval = acc[reg];                                           \
        EPILOGUE                                                               \
    }

// Kernel 8: gate GEMM; fused = sigmoid(ring@WgT^T + cg)*ring + (1-g)*center
__global__ __launch_bounds__(256) void gemm_gate_kernel(
    const __hip_bfloat16* __restrict__ A,
    const __hip_bfloat16* __restrict__ BT,
    const float* __restrict__ cg,
    const float* __restrict__ center,
    __hip_bfloat16* __restrict__ fused)
{
    GEMM_BODY({
        const int b = rg / L_;
        const float logit = aval + cg[b * N_ + col];
        const float g = 1.f / (1.f + expf(-logit));
        const float rv = __bfloat162float(A[(size_t)rg * N_ + col]);
        const float f = g * rv + (1.f - g) * center[b * N_ + col];
        fused[(size_t)rg * N_ + col] = __float2bfloat16(f);
    })
}

// ---------------------------------------------------------------------------
// Kernel 9: out GEMM + LayerNorm fused. One block = 64-row panel x all 512
// cols, 512 threads (8 waves, each owns 64 cols x 64 rows).
// Swapped-operand MFMA mfma(W_frag, data_frag): lane dim = sample row
// (verified in R3: passed), reg dim = output col. Both operands staged
// through LDS with the R2-proven coalesced global_load_lds swizzle pattern
// (fixes R3's 64-cache-line-per-instr strided B loads).
// Per K-chunk: Wsh = WfT[512][64] (64 KB), Dsh = fused[64][64] (8 KB).
// LDS ~76 KB -> 2 blocks/CU = 16 waves/CU.
// LN: each lane owns rows {row0+g*32+m32}; per-lane sums + shfl_xor(32)
// + 8-wave LDS combine (R3-verified reduce).
// ---------------------------------------------------------------------------
__global__ __launch_bounds__(512) void gemm_out_ln_kernel(
    const __hip_bfloat16* __restrict__ A,    // fused, M x 512
    const __hip_bfloat16* __restrict__ BT,   // WfT, 512 x 512 (row n = col n of Wf)
    const float* __restrict__ x,
    const float* __restrict__ bfv,
    const float* __restrict__ gamma,
    const float* __restrict__ beta,
    float* __restrict__ out)
{
    __shared__ __hip_bfloat16 Wsh[512 * 64];   // 64 KB
    __shared__ __hip_bfloat16 Dsh[64 * 64];    // 8 KB
    __shared__ float ps[8][2][32];
    __shared__ float pq[8][2][32];

    const int tid  = threadIdx.x;
    const int lane = tid & 63;
    const int wv8  = tid >> 6;        // 0..7
    const int m32  = lane & 31;
    const int half = lane >> 5;
    const int row0 = blockIdx.x * OROWS;
    const int swz  = (lane & 7) ^ (lane >> 3);
    const int rln  = lane >> 3;

    f32x16 acc[2][2];                 // [row-group g][col-subtile i]
    #pragma unroll
    for (int g = 0; g < 2; ++g)
        #pragma unroll
        for (int i = 0; i < 2; ++i) acc[g][i] = fzero16();

    for (int step = 0; step < 8; ++step) {
        const int k0 = step * 64;
        __syncthreads();
        // stage W chunk: 512 rows x 64 k, 8 issues/thread, swizzled slots
        #pragma unroll
        for (int j = 0; j < 8; ++j) {
            const int r = j * 64 + wv8 * 8 + rln;
            async_cp16(BT + (size_t)r * N_ + k0 + swz * 8,
                       Wsh + (j * 512 + wv8 * 64) * 8);
        }
        // stage fused panel chunk: 64 rows x 64 k, 1 issue/thread
        {
            const int r = wv8 * 8 + rln;
            async_cp16(A + (size_t)(row0 + r) * N_ + k0 + swz * 8,
                       Dsh + (wv8 * 64) * 8);
        }
        __syncthreads();
        #pragma unroll
        for (int ks = 0; ks < 4; ++ks) {
            const int j0 = ks * 2 + half;
            bf16x8 d0 = frag_ld(Dsh, m32, j0);
            bf16x8 d1 = frag_ld(Dsh, 32 + m32, j0);
            bf16x8 wa = frag_ld(Wsh, (wv8 * 2 + 0) * 32 + m32, j0);
            bf16x8 wb = frag_ld(Wsh, (wv8 * 2 + 1) * 32 + m32, j0);
            acc[0][0] = __builtin_amdgcn_mfma_f32_32x32x16_bf16(wa, d0, acc[0][0], 0, 0, 0);
            acc[0][1] = __builtin_amdgcn_mfma_f32_32x32x16_bf16(wb, d0, acc[0][1], 0, 0, 0);
            acc[1][0] = __builtin_amdgcn_mfma_f32_32x32x16_bf16(wa, d1, acc[1][0], 0, 0, 0);
            acc[1][1] = __builtin_amdgcn_mfma_f32_32x32x16_bf16(wb, d1, acc[1][1], 0, 0, 0);
        }
    }

    // ---- epilogue: h = acc + bf + x; accumulate LN stats ----
    float ls[2] = {0.f, 0.f};
    float lq[2] = {0.f, 0.f};
    #pragma unroll
    for (int g = 0; g < 2; ++g) {
        const int rowg = row0 + g * 32 + m32;
        #pragma unroll
        for (int i = 0; i < 2; ++i) {
            const int ntb = (wv8 * 2 + i) * 32;
            #pragma unroll
            for (int q = 0; q < 4; ++q) {
                const int nb = ntb + 8 * q + 4 * half;
                const float4 bq = *(const float4*)(bfv + nb);
                const float4 xq = *(const float4*)(x + (size_t)rowg * N_ + nb);
                float v0 = acc[g][i][4 * q + 0] + bq.x + xq.x;
                float v1 = acc[g][i][4 * q + 1] + bq.y + xq.y;
                float v2 = acc[g][i][4 * q + 2] + bq.z + xq.z;
                float v3 = acc[g][i][4 * q + 3] + bq.w + xq.w;
                acc[g][i][4 * q + 0] = v0;
                acc[g][i][4 * q + 1] = v1;
                acc[g][i][4 * q + 2] = v2;
                acc[g][i][4 * q + 3] = v3;
                ls[g] += v0 + v1 + v2 + v3;
                lq[g] += v0 * v0 + v1 * v1 + v2 * v2 + v3 * v3;
            }
        }
    }

    // ---- LN reduce: halves via shuffle, waves via LDS ----
    #pragma unroll
    for (int g = 0; g < 2; ++g) {
        ls[g] += __shfl_xor(ls[g], 32);
        lq[g] += __shfl_xor(lq[g], 32);
    }
    if (half == 0) {
        ps[wv8][0][m32] = ls[0]; pq[wv8][0][m32] = lq[0];
        ps[wv8][1][m32] = ls[1]; pq[wv8][1][m32] = lq[1];
    }
    __syncthreads();

    #pragma unroll
    for (int g = 0; g < 2; ++g) {
        float S = 0.f, Q2 = 0.f;
        #pragma unroll
        for (int w = 0; w < 8; ++w) { S += ps[w][g][m32]; Q2 += pq[w][g][m32]; }
        const float mu  = S * (1.0f / N_);
        const float var = Q2 * (1.0f / N_) - mu * mu;
        const float inv = rsqrtf(var + 1e-5f);
        const int rowg = row0 + g * 32 + m32;
        #pragma unroll
        for (int i = 0; i < 2; ++i) {
            const int ntb = (wv8 * 2 + i) * 32;
            #pragma unroll
            for (int q = 0; q < 4; ++q) {
                const int nb = ntb + 8 * q + 4 * half;
                const float4 g4 = *(const float4*)(gamma + nb);
                const float4 b4 = *(const float4*)(beta + nb);
                float4 o;
                o.x = (acc[g][i][4 * q + 0] - mu) * inv * g4.x + b4.x;
                o.y = (acc[g][i][4 * q + 1] - mu) * inv * g4.y + b4.y;
                o.z = (acc[g][i][4 * q + 2] - mu) * inv * g4.z + b4.z;
                o.w = (acc[g][i][4 * q + 3] - mu) * inv * g4.w + b4.w;
                *(float4*)(out + (size_t)rowg * N_ + nb) = o;
            }
        }
    }
}

// ---------------------------------------------------------------------------
extern "C" void kernel_launch(void* const* d_in, const int* in_sizes, int n_in,
                              void* d_out, int out_size, void* d_ws, size_t ws_size,
                              hipStream_t stream) {
    const float* x       = (const float*)d_in[0];
    const float* ve      = (const float*)d_in[1];
    const float* Wq      = (const float*)d_in[2];
    const float* bq      = (const float*)d_in[3];
    const float* Wk      = (const float*)d_in[4];
    const float* bk      = (const float*)d_in[5];
    const float* Wscore  = (const float*)d_in[6];
    const float* bscore  = (const float*)d_in[7];
    const float* Wc1     = (const float*)d_in[8];
    const float* bc1     = (const float*)d_in[9];
    const float* Wc2     = (const float*)d_in[10];
    const float* bc2     = (const float*)d_in[11];
    const float* Wcn     = (const float*)d_in[12];
    const float* bcn     = (const float*)d_in[13];
    const float* Wg      = (const float*)d_in[14];
    const float* bg      = (const float*)d_in[15];
    const float* Wf      = (const float*)d_in[16];
    const float* bf      = (const float*)d_in[17];
    const float* gamma   = (const float*)d_in[18];
    const float* beta    = (const float*)d_in[19];
    float* out = (float*)d_out;

    char* p = (char*)d_ws;
    float* ws_w    = (float*)p; p += N_ * TOPK_ * sizeof(float);
    int*   ws_idx  = (int*)p;   p += N_ * TOPK_ * sizeof(int);
    float* ws_s    = (float*)p; p += B_ * L_ * sizeof(float);
    float* ws_crp  = (float*)p; p += B_ * CRCH * N_ * sizeof(float);
    float* ws_cent = (float*)p; p += B_ * N_ * sizeof(float);
    float* ws_cg   = (float*)p; p += B_ * N_ * sizeof(float);
    float* ws_Q    = (float*)p; p += N_ * H_ * sizeof(float);
    float* ws_K    = (float*)p; p += N_ * H_ * sizeof(float);
    __hip_bfloat16* ws_ring  = (__hip_bfloat16*)p; p += (size_t)M_ * N_ * sizeof(__hip_bfloat16);
    __hip_bfloat16* ws_fused = (__hip_bfloat16*)p; p += (size_t)M_ * N_ * sizeof(__hip_bfloat16);
    __hip_bfloat16* ws_WgT   = (__hip_bfloat16*)p; p += (size_t)N_ * N_ * sizeof(__hip_bfloat16);
    __hip_bfloat16* ws_WfT   = (__hip_bfloat16*)p; p += (size_t)N_ * N_ * sizeof(__hip_bfloat16);

    convert_kernel<<<1024, 256, 0, stream>>>(Wg, Wf, ws_WgT, ws_WfT);
    qk_kernel<<<16, 512, 0, stream>>>(ve, Wq, bq, Wk, bk, ws_Q, ws_K);
    topk_kernel<<<N_, 64, 0, stream>>>(ws_Q, ws_K, ws_w, ws_idx);
    ring_kernel<<<M_ / RPB, 512, 0, stream>>>(x, ws_w, ws_idx, Wscore, bscore,
                                              ws_ring, ws_s);
    attn_softmax_kernel<<<B_, 256, 0, stream>>>(ws_s);
    center_raw_kernel<<<B_ * CRCH, 512, 0, stream>>>(x, ws_s, ws_crp);
    center_mlp_kernel<<<B_, 512, 0, stream>>>(ws_crp, Wc1, bc1, Wc2, bc2,
                                              Wcn, bcn, ws_cent);
    cg_kernel<<<dim3(8, B_), 512, 0, stream>>>(ws_cent, Wg, bg, ws_cg);
    dim3 ggrid(M_ / 64, N_ / 64);
    gemm_gate_kernel<<<ggrid, 256, 0, stream>>>(ws_ring, ws_WgT, ws_cg,
                                                ws_cent, ws_fused);
    gemm_out_ln_kernel<<<M_ / OROWS, 512, 0, stream>>>(ws_fused, ws_WfT, x, bf,
                                                       gamma, beta, out);
}